// Round 4
// baseline (123.521 us; speedup 1.0000x reference)
//
#include <hip/hip_runtime.h>
#include <hip/hip_bf16.h>

typedef __bf16 bf16_t;
typedef bf16_t bf16x4 __attribute__((ext_vector_type(4)));
typedef bf16_t bf16x8 __attribute__((ext_vector_type(8)));
typedef float  f32x4  __attribute__((ext_vector_type(4)));

#define IN_F   1024
#define OUT_F  1024
#define RANK   8
#define NE     8
#define BATCH  32
#define SEQ    1024
#define M_TOT  (BATCH * SEQ)
#define SCALE  0.125f
#define NT     16   // K / 64

#define GLOAD_LDS16(g, l)                                                     \
  __builtin_amdgcn_global_load_lds(                                           \
      (const __attribute__((address_space(1))) void*)(g),                     \
      (__attribute__((address_space(3))) void*)(l), 16, 0, 0)

#define CFENCE asm volatile("" ::: "memory")
#define BAR()                                                                 \
  do { CFENCE; __builtin_amdgcn_s_barrier(); CFENCE; } while (0)
#define VMCNT(n) asm volatile("s_waitcnt vmcnt(" #n ")" ::: "memory")
#define LGKM0()  asm volatile("s_waitcnt lgkmcnt(0)" ::: "memory")

// ---------------------------------------------------------------------------
// Kernel 1: W_eff[e][o][d] = bf16( W[o][d] + SCALE * sum_r Bw[e][o][r]*A[e][r][d] )
// ---------------------------------------------------------------------------
__global__ __launch_bounds__(256) void build_weff(
    const float* __restrict__ W, const float* __restrict__ A,
    const float* __restrict__ Bw, bf16_t* __restrict__ weff) {
  const int e  = blockIdx.x >> 10;
  const int o  = blockIdx.x & 1023;
  const int d0 = threadIdx.x << 2;

  f32x4 acc = *(const f32x4*)(W + ((size_t)o << 10) + d0);
  const float* bwr = Bw + (((size_t)e << 10) + o) * RANK;
  const float* ab  = A + (((size_t)e * RANK) << 10) + d0;
#pragma unroll
  for (int r = 0; r < RANK; ++r) {
    const float s = SCALE * bwr[r];
    const f32x4 a4 = *(const f32x4*)(ab + ((size_t)r << 10));
    acc += s * a4;
  }
  bf16x4 ov;
#pragma unroll
  for (int j = 0; j < 4; ++j) ov[j] = (bf16_t)acc[j];
  *(bf16x4*)(weff + (((size_t)e << 10) + o) * IN_F + d0) = ov;
}

// ---------------------------------------------------------------------------
// Kernel 2 (fused GEMM): 256x256, BK=64, 8 waves. A: x fp32 -> regs -> bf16
// -> ds_write into [256][64] LDS with granule^=(row&7) swizzle (conflict-free
// both sides). B: weff bf16 via global_load_lds, pre-swizzled source.
// Ledger (in-order vmcnt!), steady iter j, in-flight entering =
// [bh1(j)x2, a(j+1)x8, bh0(j+1)x2]:
//  ks0: READS(j,0); A_WRITE(j+1) [implicit wait retires bh1(j)+a(j+1)];
//       BSTAGE(j+1,kh1); A_ISSUE(j+2); BAR; MFMA; BAR.
//  ks1: READS(j,1); BSTAGE(j+2,kh0); VMCNT(12) [retires bh0(j+1) only];
//       LGKM0 [publish A(j+1)]; BAR; MFMA; BAR.
// Every VMEM op gets a full-iteration latency cover.
// ---------------------------------------------------------------------------
__global__ __launch_bounds__(512, 2) void gemm_fused(
    const float* __restrict__ xf, const bf16_t* __restrict__ weff,
    const float* __restrict__ bias, const int* __restrict__ sid,
    float* __restrict__ out) {
  __shared__ bf16_t lds_a[2][16384];     // [buf][256][64] swizzled, 64 KiB
  __shared__ bf16_t lds_b[2][2][8192];   // [buf][kh][256][32] swizzled, 64 KiB

  const int bid0 = blockIdx.x;
  const int wgid = ((bid0 & 7) << 6) + (bid0 >> 3);  // XCD chunked (512 wgs)
  const int mb = wgid >> 2, nb = wgid & 3;
  const int m0 = mb << 8, n0 = nb << 8;
  const int e = sid[mb >> 2];

  const int tid = threadIdx.x;
  const int lane = tid & 63, wid = tid >> 6;
  const int wm = wid >> 2, wn = wid & 3;

  const float*  agf    = xf + ((size_t)m0 << 10);
  const bf16_t* bgbase = weff + ((size_t)e << 20) + ((size_t)n0 << 10);

  // ---- B staging (gload_lds, pre-swizzled source granule; R2-proven) ----
  int soff[2];
#pragma unroll
  for (int i = 0; i < 2; ++i) {
    const int r = (wid << 5) + (i << 4) + (lane >> 2);
    const int sg = (lane & 3) ^ ((r >> 1) & 3);
    soff[i] = (r << 10) + (sg << 3);
  }

  // ---- A reg-staging offsets: row r=q*64+tid/8, cols (tid%8)*8..+8 ----
  int agoff[4], awoff[4];
  {
    const int c = tid & 7;                  // granule 0..7 within 64-wide row
#pragma unroll
    for (int q = 0; q < 4; ++q) {
      const int r = (q << 6) + (tid >> 3);
      agoff[q] = (r << 10) + (c << 3);
      awoff[q] = (r << 6) + ((c ^ (r & 7)) << 3);  // [256][64], XOR swizzle
    }
  }

  // ---- fragment read offsets ----
  int aoff0[8], aoff1[8], boff[4];
#pragma unroll
  for (int mi = 0; mi < 8; ++mi) {
    const int r = (wm << 7) + (mi << 4) + (lane & 15);
    const int g0 = (lane >> 4) ^ (r & 7);        // kh=0: granule 0..3 base
    const int g1 = (4 + (lane >> 4)) ^ (r & 7);  // kh=1: granule 4..7 base
    aoff0[mi] = (r << 6) + (g0 << 3);
    aoff1[mi] = (r << 6) + (g1 << 3);
  }
#pragma unroll
  for (int ni = 0; ni < 4; ++ni) {
    const int r = (wn << 6) + (ni << 4) + (lane & 15);
    const int g = (lane >> 4) ^ ((r >> 1) & 3);
    boff[ni] = (r << 5) + (g << 3);
  }

  f32x4 acc[8][4] = {};
  f32x4 ar[8];

#define A_ISSUE(kt)                                                           \
  do {                                                                        \
    const float* _x = agf + ((kt) << 6);                                      \
    _Pragma("unroll") for (int q = 0; q < 4; ++q) {                           \
      ar[2 * q]     = *(const f32x4*)(_x + agoff[q]);                         \
      ar[2 * q + 1] = *(const f32x4*)(_x + agoff[q] + 4);                     \
    }                                                                         \
  } while (0)

#define A_WRITE(kt)                                                           \
  do {                                                                        \
    bf16_t* _ab = &lds_a[(kt) & 1][0];                                        \
    _Pragma("unroll") for (int q = 0; q < 4; ++q) {                           \
      bf16x8 v;                                                               \
      _Pragma("unroll") for (int i2 = 0; i2 < 4; ++i2) {                      \
        v[i2]     = (bf16_t)ar[2 * q][i2];                                    \
        v[4 + i2] = (bf16_t)ar[2 * q + 1][i2];                                \
      }                                                                       \
      *(bf16x8*)(_ab + awoff[q]) = v;                                         \
    }                                                                         \
  } while (0)

#define BSTAGE(kt, kh)                                                        \
  do {                                                                        \
    bf16_t* _d = &lds_b[(kt) & 1][kh][wid << 10];                             \
    const int _kc = ((kt) << 6) + ((kh) << 5);                                \
    GLOAD_LDS16(bgbase + _kc + soff[0], _d);                                  \
    GLOAD_LDS16(bgbase + _kc + soff[1], _d + 512);                            \
  } while (0)

#define PHASE_READS(kt, kh)                                                   \
  do {                                                                        \
    const bf16_t* _ab = &lds_a[(kt) & 1][0];                                  \
    const bf16_t* _bb = &lds_b[(kt) & 1][kh][0];                              \
    _Pragma("unroll") for (int mi = 0; mi < 8; ++mi)                          \
        af[mi] = *(const bf16x8*)(_ab + ((kh) ? aoff1[mi] : aoff0[mi]));      \
    _Pragma("unroll") for (int ni = 0; ni < 4; ++ni)                          \
        bfr[ni] = *(const bf16x8*)(_bb + boff[ni]);                           \
  } while (0)

#define MFMAS()                                                               \
  do {                                                                        \
    __builtin_amdgcn_s_setprio(1);                                            \
    _Pragma("unroll") for (int mi = 0; mi < 8; ++mi)                          \
        _Pragma("unroll") for (int ni = 0; ni < 4; ++ni)                      \
            acc[mi][ni] = __builtin_amdgcn_mfma_f32_16x16x32_bf16(            \
                af[mi], bfr[ni], acc[mi][ni], 0, 0, 0);                       \
    __builtin_amdgcn_s_setprio(0);                                            \
  } while (0)

  // -------- prologue: establish invariant [bh1(0)x2, a(1)x8, bh0(1)x2] -----
  A_ISSUE(0);                  // a0 x8
  BSTAGE(0, 0); BSTAGE(0, 1);  // b0h0 x2, b0h1 x2
  A_WRITE(0);                  // implicit wait: retires a0 only (oldest)
  A_ISSUE(1);                  // a1 x8
  BSTAGE(1, 0);                // b1h0 x2  -> in-flight 14
  VMCNT(12);                   // retire b0h0; keep [b0h1, a1, b1h0]
  LGKM0();                     // publish A(0)
  BAR();

  bf16x8 af[8], bfr[4];
  for (int j = 0; j < NT - 2; ++j) {
    // ks0
    PHASE_READS(j, 0);
    A_WRITE(j + 1);            // implicit wait: retires bh1(j), a(j+1)
    BSTAGE(j + 1, 1);          // bh1(j+1) x2 (older than a(j+2))
    A_ISSUE(j + 2);            // a(j+2) x8
    BAR();
    MFMAS();
    BAR();
    // ks1
    PHASE_READS(j, 1);
    BSTAGE(j + 2, 0);          // bh0(j+2) x2 into freed kh0 of this buf
    VMCNT(12);                 // retires bh0(j+1) only; full-iter cover kept
    LGKM0();                   // publish A(j+1) ds_writes
    BAR();
    MFMAS();
    BAR();
  }
  // -------- tail: tile NT-2 --------
  PHASE_READS(NT - 2, 0);
  A_WRITE(NT - 1);             // implicit: retires bh1(NT-2), a(NT-1)
  BSTAGE(NT - 1, 1);
  BAR();
  MFMAS();
  BAR();
  PHASE_READS(NT - 2, 1);
  VMCNT(0);
  LGKM0();
  BAR();
  MFMAS();
  BAR();
  // -------- tile NT-1: fully resident --------
  PHASE_READS(NT - 1, 0);
  MFMAS();
  PHASE_READS(NT - 1, 1);
  MFMAS();

  // epilogue: C/D layout col=lane&15, row=(lane>>4)*4+j
  const int R0 = m0 + (wm << 7);
  const int C0 = n0 + (wn << 6);
  const int crow = (lane >> 4) << 2;
  const int ccol = lane & 15;
#pragma unroll
  for (int ni = 0; ni < 4; ++ni) {
    const int col = C0 + (ni << 4) + ccol;
    const float bv = bias[col];
#pragma unroll
    for (int mi = 0; mi < 8; ++mi) {
      const int row = R0 + (mi << 4) + crow;
#pragma unroll
      for (int j2 = 0; j2 < 4; ++j2)
        out[((size_t)(row + j2) << 10) + col] = acc[mi][ni][j2] + bv;
    }
  }
#undef A_ISSUE
#undef A_WRITE
#undef BSTAGE
#undef PHASE_READS
#undef MFMAS
}

// ---------------------------------------------------------------------------
// Fallback (ws too small): naive fp32.
// ---------------------------------------------------------------------------
__global__ __launch_bounds__(256) void lora_naive(
    const float* __restrict__ x, const float* __restrict__ W,
    const float* __restrict__ bias, const float* __restrict__ A,
    const float* __restrict__ Bw, const int* __restrict__ sid,
    float* __restrict__ out) {
  const int m = blockIdx.x;
  const int e = sid[m >> 10];
  __shared__ float xs[IN_F];
  __shared__ float h[RANK];
  const int tid = threadIdx.x;
  for (int i = tid; i < IN_F; i += 256) xs[i] = x[((size_t)m << 10) + i];
  __syncthreads();
  if (tid < RANK) {
    float s = 0.f;
    const float* ar = A + (((size_t)e * RANK + tid) << 10);
    for (int d = 0; d < IN_F; ++d) s += xs[d] * ar[d];
    h[tid] = s * SCALE;
  }
  __syncthreads();
  for (int o = tid; o < OUT_F; o += 256) {
    const float* wr = W + ((size_t)o << 10);
    float s = 0.f;
    for (int d = 0; d < IN_F; ++d) s += xs[d] * wr[d];
    const float* bwr = Bw + (((size_t)e << 10) + o) * RANK;
    float l = 0.f;
#pragma unroll
    for (int r = 0; r < RANK; ++r) l += h[r] * bwr[r];
    out[((size_t)m << 10) + o] = s + bias[o] + l;
  }
}

extern "C" void kernel_launch(void* const* d_in, const int* in_sizes, int n_in,
                              void* d_out, int out_size, void* d_ws,
                              size_t ws_size, hipStream_t stream) {
  const float* x   = (const float*)d_in[0];
  const float* W   = (const float*)d_in[1];
  const float* b   = (const float*)d_in[2];
  const float* A   = (const float*)d_in[3];
  const float* Bw  = (const float*)d_in[4];
  const int*   sid = (const int*)d_in[5];
  float* out = (float*)d_out;

  const size_t weff_bytes = (size_t)NE * OUT_F * IN_F * 2;  // 16 MiB

  if (ws_size >= weff_bytes) {
    bf16_t* weff = (bf16_t*)d_ws;
    hipLaunchKernelGGL(build_weff, dim3(NE * OUT_F), dim3(256), 0, stream,
                       W, A, Bw, weff);
    hipLaunchKernelGGL(gemm_fused, dim3((M_TOT / 256) * (OUT_F / 256)),
                       dim3(512), 0, stream, x, weff, b, sid, out);
  } else {
    hipLaunchKernelGGL(lora_naive, dim3(M_TOT), dim3(256), 0, stream,
                       x, W, b, A, Bw, sid, out);
  }
}